// Round 8
// baseline (414.370 us; speedup 1.0000x reference)
//
#include <hip/hip_runtime.h>
#include <hip/hip_bf16.h>

#define BQ   32768
#define TT   25
#define DIN  4
#define HH   32
#define GG   128
#define NBR  5
#define HIDD 64
#define WPB  8      // waves per block, all same branch, sharing LDS weights
#define LOG2E    1.4426950408889634f
#define TWOLOG2E 2.8853900817779268f

using bfrag = __attribute__((ext_vector_type(8))) short;  // 8 bf16 (4 VGPRs)
using accf  = __attribute__((ext_vector_type(4))) float;  // 4 f32 acc
using f2    = __attribute__((ext_vector_type(2))) float;  // v_pk_* candidate

__device__ __forceinline__ float fexp2(float x){
#if __has_builtin(__builtin_amdgcn_exp2f)
  return __builtin_amdgcn_exp2f(x);
#else
  return exp2f(x);
#endif
}
__device__ __forceinline__ float frcpf(float x){
#if __has_builtin(__builtin_amdgcn_rcpf)
  return __builtin_amdgcn_rcpf(x);
#else
  return 1.0f / x;
#endif
}
__device__ __forceinline__ unsigned short fb(float f){  // f32 -> bf16 bits, RNE
  unsigned u = __builtin_bit_cast(unsigned, f);
  u += 0x7fffu + ((u >> 16) & 1u);
  return (unsigned short)(u >> 16);
}
__device__ __forceinline__ bfrag pack8s(const float* p, float s){
  bfrag w;
#pragma unroll
  for (int j = 0; j < 8; ++j) w[j] = (short)fb(p[j] * s);
  return w;
}
__device__ __forceinline__ accf mma(bfrag a, bfrag b, accf c){
  return __builtin_amdgcn_mfma_f32_16x16x32_bf16(a, b, c, 0, 0, 0);
}
// Paired LSTM cell (rows r,r+1 -> consecutive VGPRs -> v_pk_* math).
// Gates pre-scaled: i,f,o by log2e; g by 2log2e. cs in 2log2e units.
// Merged-rcp form: c' = [cs*d1 + K*(t-1)*df] / (df*d1)  (one rcp, was two).
__device__ __forceinline__ f2 cellh2(f2 iv, f2 fv, f2 gv, f2 ov, f2& cs){
  const f2 one = {1.0f, 1.0f};
  f2 ei = {fexp2(-iv.x), fexp2(-iv.y)};
  f2 ef = {fexp2(-fv.x), fexp2(-fv.y)};
  f2 t  = {fexp2(gv.x),  fexp2(gv.y)};
  f2 df = one + ef;                                  // 1/sig(f) denom
  f2 d1 = (one + ei) * (t + one);                    // sig(i)*tanh(g) denom
  f2 num = cs * d1 + (f2){TWOLOG2E, TWOLOG2E} * ((t - one) * df);
  f2 den = df * d1;
  f2 rd = {frcpf(den.x), frcpf(den.y)};
  f2 cp = num * rd;
  cs = cp;
  f2 eo = {fexp2(-ov.x), fexp2(-ov.y)};
  f2 tc = {fexp2(cp.x), fexp2(cp.y)};
  f2 d3 = (one + eo) * (tc + one);
  f2 r3 = {frcpf(d3.x), frcpf(d3.y)};
  return (tc - one) * r3;                            // sig(o)*tanh(c)
}

// LDS layout (shorts):
//   wB[3][8][64][8] : Whh0/Wih1/Whh1 frag-arranged, scaled        = 12288
//   wX[8][16][8]    : layer-0 x-weight+bias frags                 =  1024
//   hb[WPB][1280]   : per-wave h0 [16][40] @ +0, h1 @ +640        = 10240
// total 23552 shorts = 47104 B -> 3 blocks/CU x 8 waves = 24 waves/CU.
#define SMEM_SH 23552

// launch_bounds(512,6): 3 blocks/CU min (= the LDS limit) -> VGPR cap ~84.
// Round 7's (512,4) accidentally capped at 64 (8 waves/SIMD for 512-thr
// blocks) and strangled scheduling; 84 is spill-safe (kernel fit in 64).
__global__ __launch_bounds__(512, 6) void lstm_kernel(
    const float* __restrict__ x,    const float* __restrict__ mask,
    const float* __restrict__ Wih0, const float* __restrict__ Whh0,
    const float* __restrict__ bih0, const float* __restrict__ bhh0,
    const float* __restrict__ Wih1, const float* __restrict__ Whh1,
    const float* __restrict__ bih1, const float* __restrict__ bhh1,
    const float* __restrict__ W1,   const float* __restrict__ b1,
    const float* __restrict__ W2,   const float* __restrict__ b2,
    float* __restrict__ out)
{
  __shared__ __align__(16) unsigned short smem[SMEM_SH];
  unsigned short* wB = smem;
  unsigned short* wX = smem + 12288;
  const int tid  = threadIdx.x;
  const int wave = tid >> 6, lane = tid & 63;
  const int col  = lane & 15, quad = lane >> 4;
  // LPT: branch 4 (L=25) blocks dispatch first; short branches backfill tail.
  const int branch = 4 - (int)(blockIdx.x >> 8);
  const int tile   = (int)(blockIdx.x & 255) * WPB + wave;
  const int batch0 = tile * 16;
  const int L = (branch + 1) * 5, t0 = TT - L;
  unsigned short* hb = smem + 13312 + wave * 1280;   // h0 @ +0, h1 @ +640

  // ---- stage the three 128x32 matrices into LDS frags (coalesced reads) ----
  {
    const float* srcs[3] = { Whh0 + branch * GG * HH,
                             Wih1 + branch * GG * HH,
                             Whh1 + branch * GG * HH };
#pragma unroll
    for (int m = 0; m < 3; ++m) {
      const float* src = srcs[m];
#pragma unroll
      for (int i = 0; i < 8; ++i) {
        int v = tid + i * 512;                 // 0..4095
        float f = src[v];
        int g = v >> 5, k = v & 31;            // gate row, k index
        float sc = ((g >> 5) == 2) ? TWOLOG2E : LOG2E;   // 'g' gate rows 64..95
        int nt = g >> 4, cv = g & 15, q = k >> 3, j = k & 7;
        wB[((m * 8 + nt) * 64 + q * 16 + cv) * 8 + j] = fb(f * sc);
      }
    }
    if (tid < 128) {   // wX: x-weights (k<4) + fused layer-0 bias (k=4)
      int nt = tid >> 4, cv = tid & 15, g = nt * 16 + cv;
      float sc = ((g >> 5) == 2) ? TWOLOG2E : LOG2E;
      const float* q4 = Wih0 + branch * GG * DIN + g * DIN;
      unsigned short* d = wX + tid * 8;
      d[0] = fb(q4[0] * sc); d[1] = fb(q4[1] * sc);
      d[2] = fb(q4[2] * sc); d[3] = fb(q4[3] * sc);
      d[4] = fb((bih0[branch * GG + g] + bhh0[branch * GG + g]) * sc);
      d[5] = 0; d[6] = 0; d[7] = 0;
    }
  }
  float bias1[8];
#pragma unroll
  for (int nt = 0; nt < 8; ++nt) {
    int g = nt * 16 + col;
    float sc = ((g >> 5) == 2) ? TWOLOG2E : LOG2E;
    bias1[nt] = (bih1[branch * GG + g] + bhh1[branch * GG + g]) * sc;
  }
  __syncthreads();   // the ONLY block barrier: weights staged

  const accf zacc = {0.f, 0.f, 0.f, 0.f};
  const f2 zf2 = {0.f, 0.f};
  bfrag aH0 = {0,0,0,0,0,0,0,0}, aH1 = {0,0,0,0,0,0,0,0};
  f2 c0[2][2] = {{zf2, zf2}, {zf2, zf2}};   // [ut][rpair]
  f2 c1[2][2] = {{zf2, zf2}, {zf2, zf2}};

  const float* xrow = x    + (size_t)(batch0 + col) * (TT * DIN);
  const float* mrow = mask + (size_t)(batch0 + col) * (TT * DIN);
  float4 xv, mv;
  if (quad == 0) {   // prefetch step t0's x
    xv = *reinterpret_cast<const float4*>(xrow + t0 * 4);
    mv = *reinterpret_cast<const float4*>(mrow + t0 * 4);
  }

  for (int s = 0; s < L; ++s) {
    // ---------- layer 0 ----------
    bfrag ax = {0,0,0,0,0,0,0,0};
    if (quad == 0) {   // A[m=col][k]: k<4 = xm_t, k=4 = 1.0 (bias lane)
      ax[0] = (short)fb(xv.x * mv.x); ax[1] = (short)fb(xv.y * mv.y);
      ax[2] = (short)fb(xv.z * mv.z); ax[3] = (short)fb(xv.w * mv.w);
      ax[4] = (short)0x3F80;
      if (s + 1 < L) {   // prefetch next step
        xv = *reinterpret_cast<const float4*>(xrow + (t0 + s + 1) * 4);
        mv = *reinterpret_cast<const float4*>(mrow + (t0 + s + 1) * 4);
      }
    }
    accf acc[8];
#pragma unroll
    for (int nt = 0; nt < 8; ++nt) {         // x + bias via MFMA (B nonzero only for quad0)
      bfrag bx = {0,0,0,0,0,0,0,0};
      if (quad == 0) bx = *reinterpret_cast<const bfrag*>(wX + (nt * 16 + col) * 8);
      acc[nt] = mma(ax, bx, zacc);
    }
#pragma unroll
    for (int nt = 0; nt < 8; ++nt) {
      bfrag bw = *reinterpret_cast<const bfrag*>(wB + ((0 * 8 + nt) * 64 + quad * 16 + col) * 8);
      acc[nt] = mma(aH0, bw, acc[nt]);
    }
#pragma unroll
    for (int ut = 0; ut < 2; ++ut)
#pragma unroll
      for (int rp = 0; rp < 2; ++rp) {       // r-pairs: consecutive VGPRs -> pk math
        f2 iv = {acc[0 + ut][rp * 2], acc[0 + ut][rp * 2 + 1]};
        f2 fv = {acc[2 + ut][rp * 2], acc[2 + ut][rp * 2 + 1]};
        f2 gv = {acc[4 + ut][rp * 2], acc[4 + ut][rp * 2 + 1]};
        f2 ov = {acc[6 + ut][rp * 2], acc[6 + ut][rp * 2 + 1]};
        f2 h = cellh2(iv, fv, gv, ov, c0[ut][rp]);
        hb[(quad * 4 + rp * 2)     * 40 + ut * 16 + col] = fb(h.x);
        hb[(quad * 4 + rp * 2 + 1) * 40 + ut * 16 + col] = fb(h.y);
      }
    aH0 = *reinterpret_cast<const bfrag*>(hb + col * 40 + quad * 8);  // A-layout (in-wave DS order)
    // ---------- layer 1 ----------
#pragma unroll
    for (int nt = 0; nt < 8; ++nt) acc[nt] = (accf){bias1[nt], bias1[nt], bias1[nt], bias1[nt]};
#pragma unroll
    for (int nt = 0; nt < 8; ++nt) {
      bfrag bw = *reinterpret_cast<const bfrag*>(wB + ((1 * 8 + nt) * 64 + quad * 16 + col) * 8);
      acc[nt] = mma(aH0, bw, acc[nt]);
    }
#pragma unroll
    for (int nt = 0; nt < 8; ++nt) {
      bfrag bw = *reinterpret_cast<const bfrag*>(wB + ((2 * 8 + nt) * 64 + quad * 16 + col) * 8);
      acc[nt] = mma(aH1, bw, acc[nt]);
    }
#pragma unroll
    for (int ut = 0; ut < 2; ++ut)
#pragma unroll
      for (int rp = 0; rp < 2; ++rp) {
        f2 iv = {acc[0 + ut][rp * 2], acc[0 + ut][rp * 2 + 1]};
        f2 fv = {acc[2 + ut][rp * 2], acc[2 + ut][rp * 2 + 1]};
        f2 gv = {acc[4 + ut][rp * 2], acc[4 + ut][rp * 2 + 1]};
        f2 ov = {acc[6 + ut][rp * 2], acc[6 + ut][rp * 2 + 1]};
        f2 h = cellh2(iv, fv, gv, ov, c1[ut][rp]);
        hb[640 + (quad * 4 + rp * 2)     * 40 + ut * 16 + col] = fb(h.x);
        hb[640 + (quad * 4 + rp * 2 + 1) * 40 + ut * 16 + col] = fb(h.y);
      }
    aH1 = *reinterpret_cast<const bfrag*>(hb + 640 + col * 40 + quad * 8);
  }

  // ---- MLP head: tmp = gelu(h1@W1T + b1); out = tmp@W2T + b2 ----
  unsigned short* fcb = hb;    // reuse h region (aH1 already in regs; in-wave DS order)
  {
    accf t1[4];
#pragma unroll
    for (int nt = 0; nt < 4; ++nt) {
      const int n = nt * 16 + col;
      bfrag bw1 = pack8s(W1 + n * HH + quad * 8, 1.0f);
      t1[nt] = (accf){b1[n], b1[n], b1[n], b1[n]};
      t1[nt] = mma(aH1, bw1, t1[nt]);
    }
#pragma unroll
    for (int nt = 0; nt < 4; ++nt)
#pragma unroll
      for (int r = 0; r < 4; ++r) {
        float v = t1[nt][r];
        v = 0.5f * v * (1.0f + erff(v * 0.70710678f));      // exact gelu
        fcb[(quad * 4 + r) * 72 + nt * 16 + col] = fb(v);
      }
  }
  bfrag af0 = *reinterpret_cast<const bfrag*>(fcb + col * 72 + quad * 8);       // k 0..31
  bfrag af1 = *reinterpret_cast<const bfrag*>(fcb + col * 72 + 32 + quad * 8);  // k 32..63
  accf o[4];
#pragma unroll
  for (int nt = 0; nt < 4; ++nt) {
    const int n = nt * 16 + col;
    bfrag bw2a = pack8s(W2 + n * HIDD + quad * 8, 1.0f);
    bfrag bw2b = pack8s(W2 + n * HIDD + 32 + quad * 8, 1.0f);
    o[nt] = (accf){b2[n], b2[n], b2[n], b2[n]};
    o[nt] = mma(af0, bw2a, o[nt]);
    o[nt] = mma(af1, bw2b, o[nt]);
  }
#pragma unroll
  for (int nt = 0; nt < 4; ++nt)
#pragma unroll
    for (int r = 0; r < 4; ++r) {
      const int row = quad * 4 + r;
      out[(size_t)((batch0 + row) * NBR + branch) * HIDD + nt * 16 + col] = o[nt][r];
    }
}

extern "C" void kernel_launch(void* const* d_in, const int* in_sizes, int n_in,
                              void* d_out, int out_size, void* d_ws, size_t ws_size,
                              hipStream_t stream) {
  const float* x    = (const float*)d_in[0];
  const float* mask = (const float*)d_in[1];
  const float* Wih0 = (const float*)d_in[2];
  const float* Whh0 = (const float*)d_in[3];
  const float* bih0 = (const float*)d_in[4];
  const float* bhh0 = (const float*)d_in[5];
  const float* Wih1 = (const float*)d_in[6];
  const float* Whh1 = (const float*)d_in[7];
  const float* bih1 = (const float*)d_in[8];
  const float* bhh1 = (const float*)d_in[9];
  const float* W1   = (const float*)d_in[10];
  const float* b1   = (const float*)d_in[11];
  const float* W2   = (const float*)d_in[12];
  const float* b2   = (const float*)d_in[13];
  float* out = (float*)d_out;

  const int nblocks = (BQ / (16 * WPB)) * NBR;   // 256 * 5 = 1280 blocks x 512 thr
  lstm_kernel<<<nblocks, 512, 0, stream>>>(x, mask, Wih0, Whh0, bih0, bhh0,
                                           Wih1, Whh1, bih1, bhh1, W1, b1, W2, b2, out);
}

// Round 9
// 261.659 us; speedup vs baseline: 1.5836x; 1.5836x over previous
//
#include <hip/hip_runtime.h>
#include <hip/hip_bf16.h>

#define BQ   32768
#define TT   25
#define DIN  4
#define HH   32
#define GG   128
#define NBR  5
#define HIDD 64
#define WPB  8      // waves per block, all same branch, sharing LDS weights
#define LOG2E    1.4426950408889634f
#define TWOLOG2E 2.8853900817779268f

using bfrag = __attribute__((ext_vector_type(8))) short;  // 8 bf16 (4 VGPRs)
using accf  = __attribute__((ext_vector_type(4))) float;  // 4 f32 acc
using f2    = __attribute__((ext_vector_type(2))) float;  // v_pk_* candidate

__device__ __forceinline__ float fexp2(float x){
#if __has_builtin(__builtin_amdgcn_exp2f)
  return __builtin_amdgcn_exp2f(x);
#else
  return exp2f(x);
#endif
}
__device__ __forceinline__ float frcpf(float x){
#if __has_builtin(__builtin_amdgcn_rcpf)
  return __builtin_amdgcn_rcpf(x);
#else
  return 1.0f / x;
#endif
}
__device__ __forceinline__ unsigned short fb(float f){  // f32 -> bf16 bits, RNE
  unsigned u = __builtin_bit_cast(unsigned, f);
  u += 0x7fffu + ((u >> 16) & 1u);
  return (unsigned short)(u >> 16);
}
__device__ __forceinline__ bfrag pack8s(const float* p, float s){
  bfrag w;
#pragma unroll
  for (int j = 0; j < 8; ++j) w[j] = (short)fb(p[j] * s);
  return w;
}
__device__ __forceinline__ accf mma(bfrag a, bfrag b, accf c){
  return __builtin_amdgcn_mfma_f32_16x16x32_bf16(a, b, c, 0, 0, 0);
}
// Paired LSTM cell (rows r,r+1 -> consecutive VGPRs -> v_pk_* math).
// Gates pre-scaled: i,f,o by log2e; g by 2log2e. cs in 2log2e units.
// Merged-rcp: c' = [cs*d1 + K*(t-1)*df] / (df*d1) -- one rcp replaces two.
// (Verified numerically in round 8: absmax identical to split form.)
__device__ __forceinline__ f2 cellh2(f2 iv, f2 fv, f2 gv, f2 ov, f2& cs){
  const f2 one = {1.0f, 1.0f};
  f2 ei = {fexp2(-iv.x), fexp2(-iv.y)};
  f2 ef = {fexp2(-fv.x), fexp2(-fv.y)};
  f2 t  = {fexp2(gv.x),  fexp2(gv.y)};
  f2 df = one + ef;                                  // 1/sig(f) denom
  f2 d1 = (one + ei) * (t + one);                    // sig(i)*tanh(g) denom
  f2 num = cs * d1 + (f2){TWOLOG2E, TWOLOG2E} * ((t - one) * df);
  f2 den = df * d1;
  f2 rd = {frcpf(den.x), frcpf(den.y)};
  f2 cp = num * rd;
  cs = cp;
  f2 eo = {fexp2(-ov.x), fexp2(-ov.y)};
  f2 tc = {fexp2(cp.x), fexp2(cp.y)};
  f2 d3 = (one + eo) * (tc + one);
  f2 r3 = {frcpf(d3.x), frcpf(d3.y)};
  return (tc - one) * r3;                            // sig(o)*tanh(c)
}

// LDS layout (shorts):
//   wB[3][8][64][8] : Whh0/Wih1/Whh1 frag-arranged, scaled        = 12288
//   wX[8][16][8]    : layer-0 x-weight+bias frags                 =  1024
//   hb[WPB][1280]   : per-wave h0 [16][40] @ +0, h1 @ +640        = 10240
// total 23552 shorts = 47104 B -> 3 blocks/CU x 8 waves.
#define SMEM_SH 23552

// launch_bounds CALIBRATION (rounds 3/7/8): total per-wave reg cap =
// 512 / min_waves_per_EU, split ~arch/AGPR. (512,4) -> 64 arch: FITS, no
// spills (round 7). (512,6) -> 40 arch: 1.2 GB spill traffic (round 8).
// Occupancy at (512,4) is VGPR-limited at 4 waves/SIMD; we are ~93%
// issue-bound anyway, so instruction count, not occupancy, is the lever.
__global__ __launch_bounds__(512, 4) void lstm_kernel(
    const float* __restrict__ x,    const float* __restrict__ mask,
    const float* __restrict__ Wih0, const float* __restrict__ Whh0,
    const float* __restrict__ bih0, const float* __restrict__ bhh0,
    const float* __restrict__ Wih1, const float* __restrict__ Whh1,
    const float* __restrict__ bih1, const float* __restrict__ bhh1,
    const float* __restrict__ W1,   const float* __restrict__ b1,
    const float* __restrict__ W2,   const float* __restrict__ b2,
    float* __restrict__ out)
{
  __shared__ __align__(16) unsigned short smem[SMEM_SH];
  unsigned short* wB = smem;
  unsigned short* wX = smem + 12288;
  const int tid  = threadIdx.x;
  const int wave = tid >> 6, lane = tid & 63;
  const int col  = lane & 15, quad = lane >> 4;
  // LPT: branch 4 (L=25) blocks dispatch first; short branches backfill tail.
  const int branch = 4 - (int)(blockIdx.x >> 8);
  const int tile   = (int)(blockIdx.x & 255) * WPB + wave;
  const int batch0 = tile * 16;
  const int L = (branch + 1) * 5, t0 = TT - L;
  unsigned short* hb = smem + 13312 + wave * 1280;   // h0 @ +0, h1 @ +640

  // ---- stage the three 128x32 matrices into LDS frags (coalesced reads) ----
  {
    const float* srcs[3] = { Whh0 + branch * GG * HH,
                             Wih1 + branch * GG * HH,
                             Whh1 + branch * GG * HH };
#pragma unroll
    for (int m = 0; m < 3; ++m) {
      const float* src = srcs[m];
#pragma unroll
      for (int i = 0; i < 8; ++i) {
        int v = tid + i * 512;                 // 0..4095
        float f = src[v];
        int g = v >> 5, k = v & 31;            // gate row, k index
        float sc = ((g >> 5) == 2) ? TWOLOG2E : LOG2E;   // 'g' gate rows 64..95
        int nt = g >> 4, cv = g & 15, q = k >> 3, j = k & 7;
        wB[((m * 8 + nt) * 64 + q * 16 + cv) * 8 + j] = fb(f * sc);
      }
    }
    if (tid < 128) {   // wX: x-weights (k<4) + fused layer-0 bias (k=4)
      int nt = tid >> 4, cv = tid & 15, g = nt * 16 + cv;
      float sc = ((g >> 5) == 2) ? TWOLOG2E : LOG2E;
      const float* q4 = Wih0 + branch * GG * DIN + g * DIN;
      unsigned short* d = wX + tid * 8;
      d[0] = fb(q4[0] * sc); d[1] = fb(q4[1] * sc);
      d[2] = fb(q4[2] * sc); d[3] = fb(q4[3] * sc);
      d[4] = fb((bih0[branch * GG + g] + bhh0[branch * GG + g]) * sc);
      d[5] = 0; d[6] = 0; d[7] = 0;
    }
  }
  float bias1[8];
#pragma unroll
  for (int nt = 0; nt < 8; ++nt) {
    int g = nt * 16 + col;
    float sc = ((g >> 5) == 2) ? TWOLOG2E : LOG2E;
    bias1[nt] = (bih1[branch * GG + g] + bhh1[branch * GG + g]) * sc;
  }
  __syncthreads();   // the ONLY block barrier: weights staged

  const accf zacc = {0.f, 0.f, 0.f, 0.f};
  const f2 zf2 = {0.f, 0.f};
  bfrag aH0 = {0,0,0,0,0,0,0,0}, aH1 = {0,0,0,0,0,0,0,0};
  f2 c0[2][2] = {{zf2, zf2}, {zf2, zf2}};   // [ut][rpair]
  f2 c1[2][2] = {{zf2, zf2}, {zf2, zf2}};

  const float* xrow = x    + (size_t)(batch0 + col) * (TT * DIN);
  const float* mrow = mask + (size_t)(batch0 + col) * (TT * DIN);
  float4 xv, mv;
  if (quad == 0) {   // prefetch step t0's x
    xv = *reinterpret_cast<const float4*>(xrow + t0 * 4);
    mv = *reinterpret_cast<const float4*>(mrow + t0 * 4);
  }

  for (int s = 0; s < L; ++s) {
    // ---------- layer 0 ----------
    bfrag ax = {0,0,0,0,0,0,0,0};
    if (quad == 0) {   // A[m=col][k]: k<4 = xm_t, k=4 = 1.0 (bias lane)
      ax[0] = (short)fb(xv.x * mv.x); ax[1] = (short)fb(xv.y * mv.y);
      ax[2] = (short)fb(xv.z * mv.z); ax[3] = (short)fb(xv.w * mv.w);
      ax[4] = (short)0x3F80;
      if (s + 1 < L) {   // prefetch next step
        xv = *reinterpret_cast<const float4*>(xrow + (t0 + s + 1) * 4);
        mv = *reinterpret_cast<const float4*>(mrow + (t0 + s + 1) * 4);
      }
    }
    accf acc[8];
#pragma unroll
    for (int nt = 0; nt < 8; ++nt) {         // x + bias via MFMA (B nonzero only for quad0)
      bfrag bx = {0,0,0,0,0,0,0,0};
      if (quad == 0) bx = *reinterpret_cast<const bfrag*>(wX + (nt * 16 + col) * 8);
      acc[nt] = mma(ax, bx, zacc);
    }
#pragma unroll
    for (int nt = 0; nt < 8; ++nt) {
      bfrag bw = *reinterpret_cast<const bfrag*>(wB + ((0 * 8 + nt) * 64 + quad * 16 + col) * 8);
      acc[nt] = mma(aH0, bw, acc[nt]);
    }
#pragma unroll
    for (int ut = 0; ut < 2; ++ut)
#pragma unroll
      for (int rp = 0; rp < 2; ++rp) {       // r-pairs: consecutive VGPRs -> pk math
        f2 iv = {acc[0 + ut][rp * 2], acc[0 + ut][rp * 2 + 1]};
        f2 fv = {acc[2 + ut][rp * 2], acc[2 + ut][rp * 2 + 1]};
        f2 gv = {acc[4 + ut][rp * 2], acc[4 + ut][rp * 2 + 1]};
        f2 ov = {acc[6 + ut][rp * 2], acc[6 + ut][rp * 2 + 1]};
        f2 h = cellh2(iv, fv, gv, ov, c0[ut][rp]);
        hb[(quad * 4 + rp * 2)     * 40 + ut * 16 + col] = fb(h.x);
        hb[(quad * 4 + rp * 2 + 1) * 40 + ut * 16 + col] = fb(h.y);
      }
    aH0 = *reinterpret_cast<const bfrag*>(hb + col * 40 + quad * 8);  // A-layout (in-wave DS order)
    // ---------- layer 1 ----------
#pragma unroll
    for (int nt = 0; nt < 8; ++nt) acc[nt] = (accf){bias1[nt], bias1[nt], bias1[nt], bias1[nt]};
#pragma unroll
    for (int nt = 0; nt < 8; ++nt) {
      bfrag bw = *reinterpret_cast<const bfrag*>(wB + ((1 * 8 + nt) * 64 + quad * 16 + col) * 8);
      acc[nt] = mma(aH0, bw, acc[nt]);
    }
#pragma unroll
    for (int nt = 0; nt < 8; ++nt) {
      bfrag bw = *reinterpret_cast<const bfrag*>(wB + ((2 * 8 + nt) * 64 + quad * 16 + col) * 8);
      acc[nt] = mma(aH1, bw, acc[nt]);
    }
#pragma unroll
    for (int ut = 0; ut < 2; ++ut)
#pragma unroll
      for (int rp = 0; rp < 2; ++rp) {
        f2 iv = {acc[0 + ut][rp * 2], acc[0 + ut][rp * 2 + 1]};
        f2 fv = {acc[2 + ut][rp * 2], acc[2 + ut][rp * 2 + 1]};
        f2 gv = {acc[4 + ut][rp * 2], acc[4 + ut][rp * 2 + 1]};
        f2 ov = {acc[6 + ut][rp * 2], acc[6 + ut][rp * 2 + 1]};
        f2 h = cellh2(iv, fv, gv, ov, c1[ut][rp]);
        hb[640 + (quad * 4 + rp * 2)     * 40 + ut * 16 + col] = fb(h.x);
        hb[640 + (quad * 4 + rp * 2 + 1) * 40 + ut * 16 + col] = fb(h.y);
      }
    aH1 = *reinterpret_cast<const bfrag*>(hb + 640 + col * 40 + quad * 8);
  }

  // ---- MLP head: tmp = gelu(h1@W1T + b1); out = tmp@W2T + b2 ----
  unsigned short* fcb = hb;    // reuse h region (aH1 already in regs; in-wave DS order)
  {
    accf t1[4];
#pragma unroll
    for (int nt = 0; nt < 4; ++nt) {
      const int n = nt * 16 + col;
      bfrag bw1 = pack8s(W1 + n * HH + quad * 8, 1.0f);
      t1[nt] = (accf){b1[n], b1[n], b1[n], b1[n]};
      t1[nt] = mma(aH1, bw1, t1[nt]);
    }
#pragma unroll
    for (int nt = 0; nt < 4; ++nt)
#pragma unroll
      for (int r = 0; r < 4; ++r) {
        float v = t1[nt][r];
        v = 0.5f * v * (1.0f + erff(v * 0.70710678f));      // exact gelu
        fcb[(quad * 4 + r) * 72 + nt * 16 + col] = fb(v);
      }
  }
  bfrag af0 = *reinterpret_cast<const bfrag*>(fcb + col * 72 + quad * 8);       // k 0..31
  bfrag af1 = *reinterpret_cast<const bfrag*>(fcb + col * 72 + 32 + quad * 8);  // k 32..63
  accf o[4];
#pragma unroll
  for (int nt = 0; nt < 4; ++nt) {
    const int n = nt * 16 + col;
    bfrag bw2a = pack8s(W2 + n * HIDD + quad * 8, 1.0f);
    bfrag bw2b = pack8s(W2 + n * HIDD + 32 + quad * 8, 1.0f);
    o[nt] = (accf){b2[n], b2[n], b2[n], b2[n]};
    o[nt] = mma(af0, bw2a, o[nt]);
    o[nt] = mma(af1, bw2b, o[nt]);
  }
#pragma unroll
  for (int nt = 0; nt < 4; ++nt)
#pragma unroll
    for (int r = 0; r < 4; ++r) {
      const int row = quad * 4 + r;
      out[(size_t)((batch0 + row) * NBR + branch) * HIDD + nt * 16 + col] = o[nt][r];
    }
}

extern "C" void kernel_launch(void* const* d_in, const int* in_sizes, int n_in,
                              void* d_out, int out_size, void* d_ws, size_t ws_size,
                              hipStream_t stream) {
  const float* x    = (const float*)d_in[0];
  const float* mask = (const float*)d_in[1];
  const float* Wih0 = (const float*)d_in[2];
  const float* Whh0 = (const float*)d_in[3];
  const float* bih0 = (const float*)d_in[4];
  const float* bhh0 = (const float*)d_in[5];
  const float* Wih1 = (const float*)d_in[6];
  const float* Whh1 = (const float*)d_in[7];
  const float* bih1 = (const float*)d_in[8];
  const float* bhh1 = (const float*)d_in[9];
  const float* W1   = (const float*)d_in[10];
  const float* b1   = (const float*)d_in[11];
  const float* W2   = (const float*)d_in[12];
  const float* b2   = (const float*)d_in[13];
  float* out = (float*)d_out;

  const int nblocks = (BQ / (16 * WPB)) * NBR;   // 256 * 5 = 1280 blocks x 512 thr
  lstm_kernel<<<nblocks, 512, 0, stream>>>(x, mask, Wih0, Whh0, bih0, bhh0,
                                           Wih1, Whh1, bih1, bhh1, W1, b1, W2, b2, out);
}